// Round 1
// baseline (23884.903 us; speedup 1.0000x reference)
//
#include <hip/hip_runtime.h>

// Bidirectional GRU, T=512, B=64, I=512, H=512, fp32 in/out.
// out layout: [T][B][2H] (fwd j in [0,H), bwd j in [H,2H)), then hT_f [B][H], hT_b [B][H].
//
// Round 1 restructure:
//   1) gi = x @ Wih^T + bih precomputed for all (dir,t) in one parallel GEMM (402 MB fp32 ws).
//   2) One persistent chain kernel: 8 independent workgroups = (batch-tile of 16) x (dir).
//      Each WG runs all 512 steps with only __syncthreads(); no grid sync needed.
//   3) Whh held in registers for the whole kernel: 96 bf16x8 fragments/wave (384 regs),
//      16 waves/WG cover all 1536 gate rows. Zero per-step weight traffic.
//   4) h state ping-pongs through XOR-swizzled LDS (bf16); fp32 h_prev stays in registers.

#define TT 512
#define BB 64
#define II 512
#define HH 512

typedef __attribute__((ext_vector_type(8))) short short8;
typedef __attribute__((ext_vector_type(4))) float f32x4;

static __device__ __forceinline__ short f2bf(float f) {
    union { float f; unsigned int u; } v; v.f = f;
    unsigned int r = (v.u + 0x7fffu + ((v.u >> 16) & 1u)) >> 16;  // RNE
    return (short)r;
}

// load 8 contiguous fp32, convert to bf16x8 fragment
static __device__ __forceinline__ short8 ldcvt(const float* __restrict__ p) {
    const float4 a = *(const float4*)p;
    const float4 b = *(const float4*)(p + 4);
    short8 r;
    r[0] = f2bf(a.x); r[1] = f2bf(a.y); r[2] = f2bf(a.z); r[3] = f2bf(a.w);
    r[4] = f2bf(b.x); r[5] = f2bf(b.y); r[6] = f2bf(b.z); r[7] = f2bf(b.w);
    return r;
}

static __device__ __forceinline__ short8 ldbf(const unsigned short* __restrict__ p) {
    return *(const short8*)p;  // 16 B
}

// Pack weights to bf16 in ws: layout [dir][gate][j][k] with k in [0,1024):
// k<512 -> Wih[g*H+j][k], k>=512 -> Whh[g*H+j][k-512]. 6.29 MB total.
__global__ __launch_bounds__(256) void convert_w_kernel(
    const float* __restrict__ Wih_f, const float* __restrict__ Whh_f,
    const float* __restrict__ Wih_b, const float* __restrict__ Whh_b,
    unsigned short* __restrict__ wsW)
{
    const int total4 = 2 * 3 * HH * 1024 / 4;
    for (int i = blockIdx.x * 256 + threadIdx.x; i < total4; i += gridDim.x * 256) {
        const int e   = i * 4;
        const int k   = e & 1023;
        const int row = e >> 10;          // 0..3071
        const int dir = row / 1536;
        const int rem = row - dir * 1536;
        const int g   = rem >> 9;         // 0..2
        const int j   = rem & 511;
        const float* W = (k < 512) ? (dir ? Wih_b : Wih_f) : (dir ? Whh_b : Whh_f);
        const int kk = k & 511;
        const float4 v = *(const float4*)&W[(size_t)(g * HH + j) * II + kk];
        unsigned short o[4] = { (unsigned short)f2bf(v.x), (unsigned short)f2bf(v.y),
                                (unsigned short)f2bf(v.z), (unsigned short)f2bf(v.w) };
        *(ushort4*)&wsW[e] = *(ushort4*)o;
    }
}

// gi[dir][t][b][g*H + j] = (x[t] @ Wih^T)[b][g*H+j] + bih[g*H+j]
// Grid (512, 2): block = one t, one dir; 4 waves, wave w owns batch rows w*16..w*16+15.
// A (x rows, bf16) cached entirely in 64 VGPRs per wave; B streamed from packed ws (L2-hot).
__global__ __launch_bounds__(256, 4) void gi_kernel(
    const float* __restrict__ inp,
    const float* __restrict__ bih_f, const float* __restrict__ bih_b,
    const unsigned short* __restrict__ wsW,
    float* __restrict__ gi)
{
    const int t    = blockIdx.x;
    const int dir  = blockIdx.y;
    const int w    = threadIdx.x >> 6;
    const int lane = threadIdx.x & 63;
    const int nm = lane & 15, kq = lane >> 4;

    short8 af[16];
    const float* xrow = inp + ((size_t)t * BB + w * 16 + nm) * II + kq * 8;
    #pragma unroll
    for (int kf = 0; kf < 16; ++kf) af[kf] = ldcvt(xrow + kf * 32);

    const float* bih = dir ? bih_b : bih_f;

    for (int g = 0; g < 3; ++g) {
        for (int jt = 0; jt < 32; ++jt) {
            f32x4 acc = {0.f, 0.f, 0.f, 0.f};
            const unsigned short* wb =
                wsW + ((size_t)((dir * 3 + g) * HH) + jt * 16 + nm) * 1024 + kq * 8;
            #pragma unroll
            for (int kf = 0; kf < 16; ++kf)
                acc = __builtin_amdgcn_mfma_f32_16x16x32_bf16(af[kf], ldbf(wb + kf * 32),
                                                              acc, 0, 0, 0);
            const int j = jt * 16 + nm;
            const float bias = bih[g * HH + j];
            float* orow = gi + (((size_t)dir * TT + t) * BB + w * 16 + kq * 4) * (3 * HH)
                             + g * HH + j;
            #pragma unroll
            for (int reg = 0; reg < 4; ++reg)
                orow[(size_t)reg * (3 * HH)] = acc[reg] + bias;
        }
    }
}

// Persistent chain kernel. Grid (4, 2): blockIdx.x = batch tile (16 rows), .y = dir.
// 1024 threads = 16 waves; wave wid owns gate columns j in [wid*32, wid*32+32) for all
// 3 gates (96 Whh rows resident in registers as 96 bf16x8 fragments).
// MODE 0: gi precomputed (fp32 in ws).  MODE 2: x-part computed inline (Wih streamed).
template <int MODE>
__global__ __launch_bounds__(1024, 1) void gru_chain_kernel(
    const float* __restrict__ inp,
    const float* __restrict__ h0f, const float* __restrict__ h0b,
    const float* __restrict__ bih_f, const float* __restrict__ bih_b,
    const float* __restrict__ bhh_f, const float* __restrict__ bhh_b,
    const unsigned short* __restrict__ wsW,
    const float* __restrict__ gi,
    float* __restrict__ out)
{
    __shared__ __align__(16) unsigned char hbuf[2][16 * 1024];  // [buf][b][k] bf16, swizzled

    const int mt   = blockIdx.x;   // 0..3
    const int dir  = blockIdx.y;   // 0..1
    const int wid  = threadIdx.x >> 6;
    const int lane = threadIdx.x & 63;
    const int nm = lane & 15, kq = lane >> 4;
    const int jw = wid * 32;

    // ---- Whh fragments resident in registers (u = g*2 + jt) ----
    short8 wf[6][16];
    #pragma unroll
    for (int g = 0; g < 3; ++g) {
        #pragma unroll
        for (int jt = 0; jt < 2; ++jt) {
            const unsigned short* wb =
                wsW + ((size_t)((dir * 3 + g) * HH) + jw + jt * 16 + nm) * 1024 + 512 + kq * 8;
            #pragma unroll
            for (int kf = 0; kf < 16; ++kf) wf[g * 2 + jt][kf] = ldbf(wb + kf * 32);
        }
    }

    const float* bhh = dir ? bhh_b : bhh_f;
    const float* bih = dir ? bih_b : bih_f;
    float bh[3][2], bi[3][2];
    #pragma unroll
    for (int g = 0; g < 3; ++g) {
        #pragma unroll
        for (int jt = 0; jt < 2; ++jt) {
            bh[g][jt] = bhh[g * HH + jw + jt * 16 + nm];
            bi[g][jt] = bih[g * HH + jw + jt * 16 + nm];
        }
    }

    // Wih row bases for MODE 2 (x-half of packed layout, k<512)
    const unsigned short* wix[6];
    #pragma unroll
    for (int g = 0; g < 3; ++g) {
        #pragma unroll
        for (int jt = 0; jt < 2; ++jt)
            wix[g * 2 + jt] =
                wsW + ((size_t)((dir * 3 + g) * HH) + jw + jt * 16 + nm) * 1024 + kq * 8;
    }

    // ---- stage h0 into LDS buf 0 (bf16, XOR-swizzled), fp32 h_prev into registers ----
    const float* h0 = dir ? h0b : h0f;
    {
        const int b = threadIdx.x >> 6;        // 0..15
        const int k = (threadIdx.x & 63) * 8;  // 0..504
        const float* p = h0 + (size_t)(mt * 16 + b) * HH + k;
        const float4 a = *(const float4*)p;
        const float4 c = *(const float4*)(p + 4);
        short8 v;
        v[0] = f2bf(a.x); v[1] = f2bf(a.y); v[2] = f2bf(a.z); v[3] = f2bf(a.w);
        v[4] = f2bf(c.x); v[5] = f2bf(c.y); v[6] = f2bf(c.z); v[7] = f2bf(c.w);
        *(short8*)(&hbuf[0][0] + b * 1024 + ((2 * k) ^ ((b & 7) << 4))) = v;
    }
    float hprev[2][4];
    #pragma unroll
    for (int jt = 0; jt < 2; ++jt) {
        #pragma unroll
        for (int reg = 0; reg < 4; ++reg)
            hprev[jt][reg] = h0[(size_t)(mt * 16 + kq * 4 + reg) * HH + jw + jt * 16 + nm];
    }
    __syncthreads();

    float* hT = out + (size_t)TT * BB * 2 * HH + (size_t)dir * BB * HH;

    for (int s = 0; s < TT; ++s) {
        const int t = dir ? (TT - 1 - s) : s;

        // prefetch gi for this step (hidden under the MFMA loop)
        float gv[2][3][4];
        if (MODE == 0) {
            const float* gb =
                gi + (((size_t)dir * TT + t) * BB + mt * 16 + kq * 4) * (3 * HH);
            #pragma unroll
            for (int jt = 0; jt < 2; ++jt) {
                #pragma unroll
                for (int g = 0; g < 3; ++g) {
                    #pragma unroll
                    for (int reg = 0; reg < 4; ++reg)
                        gv[jt][g][reg] =
                            gb[(size_t)reg * (3 * HH) + g * HH + jw + jt * 16 + nm];
                }
            }
        }

        f32x4 acc[6];
        f32x4 accx[2];
        #pragma unroll
        for (int u = 0; u < 6; ++u) acc[u] = (f32x4){0.f, 0.f, 0.f, 0.f};
        accx[0] = (f32x4){0.f, 0.f, 0.f, 0.f};
        accx[1] = (f32x4){0.f, 0.f, 0.f, 0.f};

        if (MODE == 2) {  // inline x-part: r,z fused into acc[0..3]; i_n kept in accx
            const float* xrow = inp + ((size_t)t * BB + mt * 16 + nm) * II + kq * 8;
            #pragma unroll
            for (int kf = 0; kf < 16; ++kf) {
                const short8 a = ldcvt(xrow + kf * 32);
                acc[0]  = __builtin_amdgcn_mfma_f32_16x16x32_bf16(a, ldbf(wix[0] + kf * 32), acc[0], 0, 0, 0);
                acc[1]  = __builtin_amdgcn_mfma_f32_16x16x32_bf16(a, ldbf(wix[1] + kf * 32), acc[1], 0, 0, 0);
                acc[2]  = __builtin_amdgcn_mfma_f32_16x16x32_bf16(a, ldbf(wix[2] + kf * 32), acc[2], 0, 0, 0);
                acc[3]  = __builtin_amdgcn_mfma_f32_16x16x32_bf16(a, ldbf(wix[3] + kf * 32), acc[3], 0, 0, 0);
                accx[0] = __builtin_amdgcn_mfma_f32_16x16x32_bf16(a, ldbf(wix[4] + kf * 32), accx[0], 0, 0, 0);
                accx[1] = __builtin_amdgcn_mfma_f32_16x16x32_bf16(a, ldbf(wix[5] + kf * 32), accx[1], 0, 0, 0);
            }
        }

        // recurrent half: A = h_prev (bf16, swizzled LDS), B = register-resident Whh
        const unsigned char* hb = &hbuf[s & 1][0];
        #pragma unroll
        for (int kf = 0; kf < 16; ++kf) {
            const short8 a =
                *(const short8*)(hb + nm * 1024 + ((kf * 64 + kq * 16) ^ ((nm & 7) << 4)));
            #pragma unroll
            for (int u = 0; u < 6; ++u)
                acc[u] = __builtin_amdgcn_mfma_f32_16x16x32_bf16(a, wf[u][kf], acc[u], 0, 0, 0);
        }

        // epilogue: gates, blend, write out + next LDS state
        unsigned char* hw = &hbuf[(s + 1) & 1][0];
        #pragma unroll
        for (int jt = 0; jt < 2; ++jt) {
            const int j = jw + jt * 16 + nm;
            #pragma unroll
            for (int reg = 0; reg < 4; ++reg) {
                const int bl = kq * 4 + reg;       // 0..15 within batch tile
                const int bg = mt * 16 + bl;       // global batch row
                const float i_r = (MODE == 0) ? gv[jt][0][reg] : bi[0][jt];
                const float i_z = (MODE == 0) ? gv[jt][1][reg] : bi[1][jt];
                const float i_n = (MODE == 0) ? gv[jt][2][reg] : (accx[jt][reg] + bi[2][jt]);
                const float r = 1.f / (1.f + __expf(-(acc[jt][reg]     + i_r + bh[0][jt])));
                const float z = 1.f / (1.f + __expf(-(acc[2 + jt][reg] + i_z + bh[1][jt])));
                const float n = tanhf(i_n + r * (acc[4 + jt][reg] + bh[2][jt]));
                const float h = (1.f - z) * n + z * hprev[jt][reg];
                hprev[jt][reg] = h;
                out[((size_t)t * BB + bg) * 2 * HH + dir * HH + j] = h;
                *(unsigned short*)(hw + bl * 1024 + ((2 * j) ^ ((bl & 7) << 4))) =
                    (unsigned short)f2bf(h);
                if (s == TT - 1) hT[(size_t)bg * HH + j] = h;
            }
        }
        __syncthreads();
    }
}

// ---------------- legacy fallback (tiny workspace): original per-step kernel ----------------
template <bool USE_WS>
__global__ __launch_bounds__(64) void gru_step_kernel(
    const float* __restrict__ inp,
    const float* __restrict__ h0f, const float* __restrict__ h0b,
    const float* __restrict__ Wih_f, const float* __restrict__ Whh_f,
    const float* __restrict__ bih_f, const float* __restrict__ bhh_f,
    const float* __restrict__ Wih_b, const float* __restrict__ Whh_b,
    const float* __restrict__ bih_b, const float* __restrict__ bhh_b,
    const unsigned short* __restrict__ wsW,
    float* __restrict__ out, int s)
{
    const int jt   = blockIdx.x;
    const int mt   = blockIdx.y;
    const int dir  = blockIdx.z;
    const int lane = threadIdx.x;
    const int nm   = lane & 15;
    const int kq   = lane >> 4;
    const int j0   = jt * 16;
    const int koff = kq * 8;

    const int t  = dir ? (TT - 1 - s) : s;
    const int tp = dir ? (t + 1) : (t - 1);

    const float* Wih = dir ? Wih_b : Wih_f;
    const float* Whh = dir ? Whh_b : Whh_f;
    const float* bih = dir ? bih_b : bih_f;
    const float* bhh = dir ? bhh_b : bhh_f;
    const float* h0  = dir ? h0b : h0f;

    const int arow = mt * 16 + nm;

    const float* xrow = inp + ((size_t)t * BB + arow) * II;
    const float* hrow = (s == 0) ? (h0 + (size_t)arow * HH)
                                 : (out + ((size_t)tp * BB + arow) * 2 * HH + dir * HH);

    const float* wi0 = Wih + (size_t)(0 * HH + j0 + nm) * II;
    const float* wi1 = Wih + (size_t)(1 * HH + j0 + nm) * II;
    const float* wi2 = Wih + (size_t)(2 * HH + j0 + nm) * II;
    const float* wh0 = Whh + (size_t)(0 * HH + j0 + nm) * II;
    const float* wh1 = Whh + (size_t)(1 * HH + j0 + nm) * II;
    const float* wh2 = Whh + (size_t)(2 * HH + j0 + nm) * II;

    f32x4 ar = {0.f, 0.f, 0.f, 0.f};
    f32x4 az = ar, ain = ar, ahn = ar;

    #pragma unroll 4
    for (int k0 = 0; k0 < II; k0 += 32) {
        const int kk = k0 + koff;
        const short8 a  = ldcvt(xrow + kk);
        const short8 b0 = ldcvt(wi0 + kk);
        const short8 b1 = ldcvt(wi1 + kk);
        const short8 b2 = ldcvt(wi2 + kk);
        ar  = __builtin_amdgcn_mfma_f32_16x16x32_bf16(a, b0, ar, 0, 0, 0);
        az  = __builtin_amdgcn_mfma_f32_16x16x32_bf16(a, b1, az, 0, 0, 0);
        ain = __builtin_amdgcn_mfma_f32_16x16x32_bf16(a, b2, ain, 0, 0, 0);
    }
    #pragma unroll 4
    for (int k0 = 0; k0 < HH; k0 += 32) {
        const int kk = k0 + koff;
        const short8 a  = ldcvt(hrow + kk);
        const short8 b0 = ldcvt(wh0 + kk);
        const short8 b1 = ldcvt(wh1 + kk);
        const short8 b2 = ldcvt(wh2 + kk);
        ar  = __builtin_amdgcn_mfma_f32_16x16x32_bf16(a, b0, ar, 0, 0, 0);
        az  = __builtin_amdgcn_mfma_f32_16x16x32_bf16(a, b1, az, 0, 0, 0);
        ahn = __builtin_amdgcn_mfma_f32_16x16x32_bf16(a, b2, ahn, 0, 0, 0);
    }

    const int jg = j0 + nm;
    const float b_ir = bih[jg], b_iz = bih[HH + jg], b_in = bih[2 * HH + jg];
    const float b_hr = bhh[jg], b_hz = bhh[HH + jg], b_hn = bhh[2 * HH + jg];

    #pragma unroll
    for (int rg = 0; rg < 4; ++rg) {
        const int be = mt * 16 + kq * 4 + rg;
        const float hprevv = (s == 0)
            ? h0[(size_t)be * HH + jg]
            : out[((size_t)tp * BB + be) * 2 * HH + dir * HH + jg];
        const float r = 1.f / (1.f + __expf(-(ar[rg] + b_ir + b_hr)));
        const float z = 1.f / (1.f + __expf(-(az[rg] + b_iz + b_hz)));
        const float n = tanhf(ain[rg] + b_in + r * (ahn[rg] + b_hn));
        const float hnew = (1.f - z) * n + z * hprevv;
        out[((size_t)t * BB + be) * 2 * HH + dir * HH + jg] = hnew;
        if (s == TT - 1) {
            float* hTp = out + (size_t)TT * BB * 2 * HH + (size_t)dir * BB * HH;
            hTp[(size_t)be * HH + jg] = hnew;
        }
    }
}

extern "C" void kernel_launch(void* const* d_in, const int* in_sizes, int n_in,
                              void* d_out, int out_size, void* d_ws, size_t ws_size,
                              hipStream_t stream) {
    (void)in_sizes; (void)n_in; (void)out_size;

    const float* inp   = (const float*)d_in[0];
    const float* h0f   = (const float*)d_in[1];
    const float* h0b   = (const float*)d_in[2];
    const float* Wih_f = (const float*)d_in[3];
    const float* Whh_f = (const float*)d_in[4];
    const float* bih_f = (const float*)d_in[5];
    const float* bhh_f = (const float*)d_in[6];
    const float* Wih_b = (const float*)d_in[7];
    const float* Whh_b = (const float*)d_in[8];
    const float* bih_b = (const float*)d_in[9];
    const float* bhh_b = (const float*)d_in[10];
    float* out = (float*)d_out;

    const size_t W_BYTES  = (size_t)2 * 3 * HH * 1024 * sizeof(unsigned short);  // 6.29 MB
    const size_t GI_BYTES = (size_t)2 * TT * BB * 3 * HH * sizeof(float);        // 402.7 MB

    if (ws_size >= W_BYTES + GI_BYTES) {
        unsigned short* wsW = (unsigned short*)d_ws;
        float* gi = (float*)((char*)d_ws + W_BYTES);
        convert_w_kernel<<<1024, 256, 0, stream>>>(Wih_f, Whh_f, Wih_b, Whh_b, wsW);
        gi_kernel<<<dim3(TT, 2), 256, 0, stream>>>(inp, bih_f, bih_b, wsW, gi);
        gru_chain_kernel<0><<<dim3(4, 2), 1024, 0, stream>>>(
            inp, h0f, h0b, bih_f, bih_b, bhh_f, bhh_b, wsW, gi, out);
    } else if (ws_size >= W_BYTES) {
        unsigned short* wsW = (unsigned short*)d_ws;
        convert_w_kernel<<<1024, 256, 0, stream>>>(Wih_f, Whh_f, Wih_b, Whh_b, wsW);
        gru_chain_kernel<2><<<dim3(4, 2), 1024, 0, stream>>>(
            inp, h0f, h0b, bih_f, bih_b, bhh_f, bhh_b, wsW, nullptr, out);
    } else {
        const dim3 grid(HH / 16, BB / 16, 2);
        for (int s = 0; s < TT; ++s) {
            gru_step_kernel<false><<<grid, dim3(64), 0, stream>>>(
                inp, h0f, h0b, Wih_f, Whh_f, bih_f, bhh_f,
                Wih_b, Whh_b, bih_b, bhh_b, nullptr, out, s);
        }
    }
}

// Round 2
// 5130.885 us; speedup vs baseline: 4.6551x; 4.6551x over previous
//
#include <hip/hip_runtime.h>

// Bidirectional GRU, T=512, B=64, I=512, H=512, fp32 in/out.
// out layout: [T][B][2H] (fwd j in [0,H), bwd j in [H,2H)), then hT_f [B][H], hT_b [B][H].
//
// Round 2 structure:
//   1) convert_w: pack Wih|Whh to bf16 ws (+ reset per-chain sync flags).
//   2) gi_kernel: gi[dir][t][g][j][b] = x @ Wih^T + bih, fp32 (402 MB ws).
//   3) gru_chain_coop (cooperative, 32 WGs x 512 thr): chain = (batch-tile 16, dir),
//      4 WGs per chain each owning a j-quarter (128 j). Whh fragments register-resident
//      (48 frags = 192 VGPR per wave; three 16-elem arrays, fully unrolled -> SROA).
//      h state ping-pongs via global bf16 buffer; per-chain epoch-counter sync
//      (release atomicAdd / acquire spin), chain's 4 WGs on one XCD via bid&7.

#define TT 512
#define BB 64
#define II 512
#define HH 512

typedef __attribute__((ext_vector_type(8))) short short8;
typedef __attribute__((ext_vector_type(4))) float f32x4;

static __device__ __forceinline__ short f2bf(float f) {
    union { float f; unsigned int u; } v; v.f = f;
    unsigned int r = (v.u + 0x7fffu + ((v.u >> 16) & 1u)) >> 16;  // RNE
    return (short)r;
}

static __device__ __forceinline__ short8 ldcvt(const float* __restrict__ p) {
    const float4 a = *(const float4*)p;
    const float4 b = *(const float4*)(p + 4);
    short8 r;
    r[0] = f2bf(a.x); r[1] = f2bf(a.y); r[2] = f2bf(a.z); r[3] = f2bf(a.w);
    r[4] = f2bf(b.x); r[5] = f2bf(b.y); r[6] = f2bf(b.z); r[7] = f2bf(b.w);
    return r;
}

static __device__ __forceinline__ short8 ldbf(const unsigned short* __restrict__ p) {
    return *(const short8*)p;  // 16 B
}

// Pack weights to bf16 in ws: [dir][gate][j][k], k<512 -> Wih, k>=512 -> Whh. 6.29 MB.
// Also resets the 8 per-chain sync counters (flags may be null on fallback paths).
__global__ __launch_bounds__(256) void convert_w_kernel(
    const float* __restrict__ Wih_f, const float* __restrict__ Whh_f,
    const float* __restrict__ Wih_b, const float* __restrict__ Whh_b,
    unsigned short* __restrict__ wsW, unsigned int* __restrict__ flags)
{
    if (flags && blockIdx.x == 0 && threadIdx.x < 8) flags[threadIdx.x] = 0u;
    const int total4 = 2 * 3 * HH * 1024 / 4;
    for (int i = blockIdx.x * 256 + threadIdx.x; i < total4; i += gridDim.x * 256) {
        const int e   = i * 4;
        const int k   = e & 1023;
        const int row = e >> 10;          // 0..3071
        const int dir = row / 1536;
        const int rem = row - dir * 1536;
        const int g   = rem >> 9;         // 0..2
        const int j   = rem & 511;
        const float* W = (k < 512) ? (dir ? Wih_b : Wih_f) : (dir ? Whh_b : Whh_f);
        const int kk = k & 511;
        const float4 v = *(const float4*)&W[(size_t)(g * HH + j) * II + kk];
        unsigned short o[4] = { (unsigned short)f2bf(v.x), (unsigned short)f2bf(v.y),
                                (unsigned short)f2bf(v.z), (unsigned short)f2bf(v.w) };
        *(ushort4*)&wsW[e] = *(ushort4*)o;
    }
}

// gi[dir][t][g][j][b] = (x[t] @ Wih^T)[b][g*H+j] + bih[g*H+j]   (fp32)
// Grid (512, 2): block = one t, one dir; 4 waves; wave w owns batch rows w*16..w*16+15.
__global__ __launch_bounds__(256, 4) void gi_kernel(
    const float* __restrict__ inp,
    const float* __restrict__ bih_f, const float* __restrict__ bih_b,
    const unsigned short* __restrict__ wsW,
    float* __restrict__ gi)
{
    const int t    = blockIdx.x;
    const int dir  = blockIdx.y;
    const int w    = threadIdx.x >> 6;
    const int lane = threadIdx.x & 63;
    const int nm = lane & 15, kq = lane >> 4;

    short8 af[16];
    const float* xrow = inp + ((size_t)t * BB + w * 16 + nm) * II + kq * 8;
    #pragma unroll
    for (int kf = 0; kf < 16; ++kf) af[kf] = ldcvt(xrow + kf * 32);

    const float* bih = dir ? bih_b : bih_f;

    for (int g = 0; g < 3; ++g) {
        for (int jt = 0; jt < 32; ++jt) {
            f32x4 acc = {0.f, 0.f, 0.f, 0.f};
            const unsigned short* wb =
                wsW + ((size_t)((dir * 3 + g) * HH) + jt * 16 + nm) * 1024 + kq * 8;
            #pragma unroll
            for (int kf = 0; kf < 16; ++kf)
                acc = __builtin_amdgcn_mfma_f32_16x16x32_bf16(af[kf], ldbf(wb + kf * 32),
                                                              acc, 0, 0, 0);
            const int jj = jt * 16 + nm;
            const float bias = bih[g * HH + jj];
            float4 o;
            o.x = acc[0] + bias; o.y = acc[1] + bias;
            o.z = acc[2] + bias; o.w = acc[3] + bias;
            // layout: (((dir*T + t)*3 + g) * 512*64) + j*64 + b
            *(float4*)(gi + (((size_t)dir * TT + t) * 3 + g) * (HH * BB)
                         + (size_t)jj * BB + w * 16 + kq * 4) = o;
        }
    }
}

// Persistent cooperative chain kernel. 32 WGs x 512 threads.
// chain = bid & 7 (same XCD for a chain's 4 WGs), quarter = bid >> 3.
// chain -> mt = chain & 3 (batch tile of 16), dir = chain >> 2.
// Wave wid owns j = quarter*128 + wid*16 + nm for all 3 gates.
__global__ __launch_bounds__(512, 1) void gru_chain_coop(
    const float* __restrict__ h0f, const float* __restrict__ h0b,
    const float* __restrict__ bhh_f, const float* __restrict__ bhh_b,
    const unsigned short* __restrict__ wsW,
    const float* __restrict__ gi,
    unsigned short* __restrict__ hbuf,   // [2][8][16][512] bf16
    unsigned int* __restrict__ flags,    // [8] epoch counters
    float* __restrict__ out)
{
    const int bid     = blockIdx.x;
    const int chain   = bid & 7;
    const int quarter = bid >> 3;
    const int mt  = chain & 3;
    const int dir = chain >> 2;
    const int tid  = threadIdx.x;
    const int wid  = tid >> 6;
    const int lane = tid & 63;
    const int nm = lane & 15, kq = lane >> 4;
    const int j = quarter * 128 + wid * 16 + nm;   // this lane's gate column

    // ---- register-resident Whh fragments (k = 512..1023 of packed row) ----
    short8 wfr[16], wfz[16], wfn[16];
    {
        const unsigned short* w0 =
            wsW + ((size_t)((dir * 3 + 0) * HH) + j) * 1024 + 512 + kq * 8;
        const unsigned short* w1 = w0 + (size_t)HH * 1024;
        const unsigned short* w2 = w0 + (size_t)2 * HH * 1024;
        #pragma unroll
        for (int kf = 0; kf < 16; ++kf) {
            wfr[kf] = ldbf(w0 + kf * 32);
            wfz[kf] = ldbf(w1 + kf * 32);
            wfn[kf] = ldbf(w2 + kf * 32);
        }
    }

    const float* bhh = dir ? bhh_b : bhh_f;
    const float bhr = bhh[j], bhz = bhh[HH + j], bhn = bhh[2 * HH + j];

    // ---- stage h0 -> hbuf[0][chain] (each WG writes the full copy; identical data) ----
    const float* h0 = dir ? h0b : h0f;
    unsigned short* hb0 = hbuf + (size_t)chain * (16 * 512);
    {
        const int bl = tid >> 5;          // 0..15
        const int k0 = (tid & 31) * 16;   // 0..496
        const float* p = h0 + (size_t)(mt * 16 + bl) * HH + k0;
        *(short8*)(hb0 + (size_t)bl * 512 + k0)     = ldcvt(p);
        *(short8*)(hb0 + (size_t)bl * 512 + k0 + 8) = ldcvt(p + 8);
    }
    float hprev[4];
    #pragma unroll
    for (int rg = 0; rg < 4; ++rg)
        hprev[rg] = h0[(size_t)(mt * 16 + kq * 4 + rg) * HH + j];
    __syncthreads();

    unsigned int* ctr = flags + chain;

    // gi for step 0, prefetched
    f32x4 gr, gz, gn;
    {
        const int t0 = dir ? (TT - 1) : 0;
        const float* gb = gi + (((size_t)dir * TT + t0) * 3) * (HH * BB)
                             + (size_t)j * BB + mt * 16 + kq * 4;
        gr = *(const f32x4*)(gb);
        gz = *(const f32x4*)(gb + HH * BB);
        gn = *(const f32x4*)(gb + 2 * HH * BB);
    }

    for (int s = 0; s < TT; ++s) {
        const int t = dir ? (TT - 1 - s) : s;
        const unsigned short* hb = hbuf + ((size_t)(s & 1) * 8 + chain) * (16 * 512);
        unsigned short* hw = hbuf + ((size_t)((s + 1) & 1) * 8 + chain) * (16 * 512);

        // A fragments: h_prev rows (batch = nm), contiguous k
        short8 ha[16];
        const unsigned short* hrow = hb + (size_t)nm * 512 + kq * 8;
        #pragma unroll
        for (int kf = 0; kf < 16; ++kf) ha[kf] = ldbf(hrow + kf * 32);

        f32x4 ar = {0.f, 0.f, 0.f, 0.f};
        f32x4 az = ar, an = ar;
        #pragma unroll
        for (int kf = 0; kf < 16; ++kf) {
            ar = __builtin_amdgcn_mfma_f32_16x16x32_bf16(ha[kf], wfr[kf], ar, 0, 0, 0);
            az = __builtin_amdgcn_mfma_f32_16x16x32_bf16(ha[kf], wfz[kf], az, 0, 0, 0);
            an = __builtin_amdgcn_mfma_f32_16x16x32_bf16(ha[kf], wfn[kf], an, 0, 0, 0);
        }

        // epilogue: gates + blend; write out fp32 + next h state bf16
        float* orow = out + ((size_t)t * BB + mt * 16 + kq * 4) * (2 * HH) + dir * HH + j;
        #pragma unroll
        for (int rg = 0; rg < 4; ++rg) {
            const float r = 1.f / (1.f + __expf(-(ar[rg] + gr[rg] + bhr)));
            const float z = 1.f / (1.f + __expf(-(az[rg] + gz[rg] + bhz)));
            const float n = tanhf(gn[rg] + r * (an[rg] + bhn));
            const float h = (1.f - z) * n + z * hprev[rg];
            hprev[rg] = h;
            orow[(size_t)rg * 2 * HH] = h;
            hw[(size_t)(kq * 4 + rg) * 512 + j] = (unsigned short)f2bf(h);
        }
        if (s == TT - 1) {
            float* hT = out + (size_t)TT * BB * 2 * HH + (size_t)dir * BB * HH;
            #pragma unroll
            for (int rg = 0; rg < 4; ++rg)
                hT[(size_t)(mt * 16 + kq * 4 + rg) * HH + j] = hprev[rg];
        } else {
            // prefetch next step's gi across the barrier (read-only data)
            const int tn = dir ? (TT - 2 - s) : (s + 1);
            const float* gb = gi + (((size_t)dir * TT + tn) * 3) * (HH * BB)
                                 + (size_t)j * BB + mt * 16 + kq * 4;
            gr = *(const f32x4*)(gb);
            gz = *(const f32x4*)(gb + HH * BB);
            gn = *(const f32x4*)(gb + 2 * HH * BB);

            // per-chain epoch barrier (4 WGs)
            __syncthreads();
            if (tid == 0) {
                __hip_atomic_fetch_add(ctr, 1u, __ATOMIC_RELEASE, __HIP_MEMORY_SCOPE_AGENT);
                const unsigned int want = 4u * (unsigned int)(s + 1);
                while (__hip_atomic_load(ctr, __ATOMIC_ACQUIRE,
                                         __HIP_MEMORY_SCOPE_AGENT) < want)
                    __builtin_amdgcn_s_sleep(1);
            }
            __syncthreads();
        }
    }
}

// ---------------- fallback: per-step kernel (round-0 verified) ----------------
template <bool USE_WS>
__global__ __launch_bounds__(64) void gru_step_kernel(
    const float* __restrict__ inp,
    const float* __restrict__ h0f, const float* __restrict__ h0b,
    const float* __restrict__ Wih_f, const float* __restrict__ Whh_f,
    const float* __restrict__ bih_f, const float* __restrict__ bhh_f,
    const float* __restrict__ Wih_b, const float* __restrict__ Whh_b,
    const float* __restrict__ bih_b, const float* __restrict__ bhh_b,
    const unsigned short* __restrict__ wsW,
    float* __restrict__ out, int s)
{
    const int jt   = blockIdx.x;
    const int mt   = blockIdx.y;
    const int dir  = blockIdx.z;
    const int lane = threadIdx.x;
    const int nm   = lane & 15;
    const int kq   = lane >> 4;
    const int j0   = jt * 16;
    const int koff = kq * 8;

    const int t  = dir ? (TT - 1 - s) : s;
    const int tp = dir ? (t + 1) : (t - 1);

    const float* Wih = dir ? Wih_b : Wih_f;
    const float* Whh = dir ? Whh_b : Whh_f;
    const float* bih = dir ? bih_b : bih_f;
    const float* bhh = dir ? bhh_b : bhh_f;
    const float* h0  = dir ? h0b : h0f;

    const int arow = mt * 16 + nm;

    const float* xrow = inp + ((size_t)t * BB + arow) * II;
    const float* hrow = (s == 0) ? (h0 + (size_t)arow * HH)
                                 : (out + ((size_t)tp * BB + arow) * 2 * HH + dir * HH);

    const unsigned short* wb0 = nullptr; const unsigned short* wb1 = nullptr;
    const unsigned short* wb2 = nullptr;
    if (USE_WS) {
        const size_t base = ((size_t)(dir * 3 + 0) * HH + (j0 + nm)) * 1024;
        wb0 = wsW + base;
        wb1 = wsW + base + (size_t)HH * 1024;
        wb2 = wsW + base + (size_t)2 * HH * 1024;
    }
    const float* wi0 = Wih + (size_t)(0 * HH + j0 + nm) * II;
    const float* wi1 = Wih + (size_t)(1 * HH + j0 + nm) * II;
    const float* wi2 = Wih + (size_t)(2 * HH + j0 + nm) * II;
    const float* wh0 = Whh + (size_t)(0 * HH + j0 + nm) * II;
    const float* wh1 = Whh + (size_t)(1 * HH + j0 + nm) * II;
    const float* wh2 = Whh + (size_t)(2 * HH + j0 + nm) * II;

    f32x4 ar = {0.f, 0.f, 0.f, 0.f};
    f32x4 az = ar, ain = ar, ahn = ar;

    #pragma unroll 4
    for (int k0 = 0; k0 < II; k0 += 32) {
        const int kk = k0 + koff;
        const short8 a  = ldcvt(xrow + kk);
        const short8 b0 = USE_WS ? ldbf(wb0 + kk) : ldcvt(wi0 + kk);
        const short8 b1 = USE_WS ? ldbf(wb1 + kk) : ldcvt(wi1 + kk);
        const short8 b2 = USE_WS ? ldbf(wb2 + kk) : ldcvt(wi2 + kk);
        ar  = __builtin_amdgcn_mfma_f32_16x16x32_bf16(a, b0, ar, 0, 0, 0);
        az  = __builtin_amdgcn_mfma_f32_16x16x32_bf16(a, b1, az, 0, 0, 0);
        ain = __builtin_amdgcn_mfma_f32_16x16x32_bf16(a, b2, ain, 0, 0, 0);
    }
    #pragma unroll 4
    for (int k0 = 0; k0 < HH; k0 += 32) {
        const int kk = k0 + koff;
        const short8 a  = ldcvt(hrow + kk);
        const short8 b0 = USE_WS ? ldbf(wb0 + 512 + kk) : ldcvt(wh0 + kk);
        const short8 b1 = USE_WS ? ldbf(wb1 + 512 + kk) : ldcvt(wh1 + kk);
        const short8 b2 = USE_WS ? ldbf(wb2 + 512 + kk) : ldcvt(wh2 + kk);
        ar  = __builtin_amdgcn_mfma_f32_16x16x32_bf16(a, b0, ar, 0, 0, 0);
        az  = __builtin_amdgcn_mfma_f32_16x16x32_bf16(a, b1, az, 0, 0, 0);
        ahn = __builtin_amdgcn_mfma_f32_16x16x32_bf16(a, b2, ahn, 0, 0, 0);
    }

    const int jg = j0 + nm;
    const float b_ir = bih[jg], b_iz = bih[HH + jg], b_in = bih[2 * HH + jg];
    const float b_hr = bhh[jg], b_hz = bhh[HH + jg], b_hn = bhh[2 * HH + jg];

    #pragma unroll
    for (int rg = 0; rg < 4; ++rg) {
        const int be = mt * 16 + kq * 4 + rg;
        const float hprevv = (s == 0)
            ? h0[(size_t)be * HH + jg]
            : out[((size_t)tp * BB + be) * 2 * HH + dir * HH + jg];
        const float r = 1.f / (1.f + __expf(-(ar[rg] + b_ir + b_hr)));
        const float z = 1.f / (1.f + __expf(-(az[rg] + b_iz + b_hz)));
        const float n = tanhf(ain[rg] + b_in + r * (ahn[rg] + b_hn));
        const float hnew = (1.f - z) * n + z * hprevv;
        out[((size_t)t * BB + be) * 2 * HH + dir * HH + jg] = hnew;
        if (s == TT - 1) {
            float* hTp = out + (size_t)TT * BB * 2 * HH + (size_t)dir * BB * HH;
            hTp[(size_t)be * HH + jg] = hnew;
        }
    }
}

extern "C" void kernel_launch(void* const* d_in, const int* in_sizes, int n_in,
                              void* d_out, int out_size, void* d_ws, size_t ws_size,
                              hipStream_t stream) {
    (void)in_sizes; (void)n_in; (void)out_size;

    const float* inp   = (const float*)d_in[0];
    const float* h0f   = (const float*)d_in[1];
    const float* h0b   = (const float*)d_in[2];
    const float* Wih_f = (const float*)d_in[3];
    const float* Whh_f = (const float*)d_in[4];
    const float* bih_f = (const float*)d_in[5];
    const float* bhh_f = (const float*)d_in[6];
    const float* Wih_b = (const float*)d_in[7];
    const float* Whh_b = (const float*)d_in[8];
    const float* bih_b = (const float*)d_in[9];
    const float* bhh_b = (const float*)d_in[10];
    float* out = (float*)d_out;

    const size_t W_BYTES  = (size_t)2 * 3 * HH * 1024 * sizeof(unsigned short);   // 6.29 MB
    const size_t GI_BYTES = (size_t)2 * TT * 3 * HH * BB * sizeof(float);         // 402.7 MB
    const size_t HB_BYTES = (size_t)2 * 8 * 16 * 512 * sizeof(unsigned short);    // 256 KB
    const size_t FL_BYTES = 256;

    if (ws_size >= W_BYTES + GI_BYTES + HB_BYTES + FL_BYTES) {
        unsigned short* wsW  = (unsigned short*)d_ws;
        float*          gi   = (float*)((char*)d_ws + W_BYTES);
        unsigned short* hbuf = (unsigned short*)((char*)d_ws + W_BYTES + GI_BYTES);
        unsigned int*   flags = (unsigned int*)((char*)d_ws + W_BYTES + GI_BYTES + HB_BYTES);

        convert_w_kernel<<<1024, 256, 0, stream>>>(Wih_f, Whh_f, Wih_b, Whh_b, wsW, flags);
        gi_kernel<<<dim3(TT, 2), 256, 0, stream>>>(inp, bih_f, bih_b, wsW, gi);

        void* args[] = { (void*)&h0f, (void*)&h0b, (void*)&bhh_f, (void*)&bhh_b,
                         (void*)&wsW, (void*)&gi, (void*)&hbuf, (void*)&flags,
                         (void*)&out };
        hipLaunchCooperativeKernel((const void*)gru_chain_coop,
                                   dim3(32), dim3(512), args, 0, stream);
    } else if (ws_size >= W_BYTES) {
        unsigned short* wsW = (unsigned short*)d_ws;
        convert_w_kernel<<<1024, 256, 0, stream>>>(Wih_f, Whh_f, Wih_b, Whh_b, wsW, nullptr);
        const dim3 grid(HH / 16, BB / 16, 2);
        for (int s = 0; s < TT; ++s) {
            gru_step_kernel<true><<<grid, dim3(64), 0, stream>>>(
                inp, h0f, h0b, Wih_f, Whh_f, bih_f, bhh_f,
                Wih_b, Whh_b, bih_b, bhh_b, wsW, out, s);
        }
    } else {
        const dim3 grid(HH / 16, BB / 16, 2);
        for (int s = 0; s < TT; ++s) {
            gru_step_kernel<false><<<grid, dim3(64), 0, stream>>>(
                inp, h0f, h0b, Wih_f, Whh_f, bih_f, bhh_f,
                Wih_b, Whh_b, bih_b, bhh_b, nullptr, out, s);
        }
    }
}

// Round 6
// 3836.370 us; speedup vs baseline: 6.2259x; 1.3374x over previous
//
#include <hip/hip_runtime.h>

// Bidirectional GRU, T=512, B=64, I=512, H=512, fp32 in/out.
// out layout: [T][B][2H] (fwd j in [0,H), bwd j in [H,2H)), then hT_f [B][H], hT_b [B][H].
//
// Round 6:
//   - Topology/sync = round-2 VERBATIM (the only HW-proven coop config):
//     32 WGs x 512 thr, 4 WGs/chain, stride-1 flags, RELEASE add + ACQUIRE-poll.
//   - Register fix: ha[16] (64 regs) eliminated -- h tile staged global->LDS once
//     per step (16 KB, XOR-swizzled) and A-fragments read per-kf from LDS.
//     Weight residency now fits the 8-wave budget: 192 (Whh) + ~55 working <= 256.
//     Declared with __launch_bounds__(512, 2).

#define TT 512
#define BB 64
#define II 512
#define HH 512

typedef __attribute__((ext_vector_type(8))) short short8;
typedef __attribute__((ext_vector_type(4))) float f32x4;

static __device__ __forceinline__ short f2bf(float f) {
    union { float f; unsigned int u; } v; v.f = f;
    unsigned int r = (v.u + 0x7fffu + ((v.u >> 16) & 1u)) >> 16;  // RNE
    return (short)r;
}

static __device__ __forceinline__ short8 ldcvt(const float* __restrict__ p) {
    const float4 a = *(const float4*)p;
    const float4 b = *(const float4*)(p + 4);
    short8 r;
    r[0] = f2bf(a.x); r[1] = f2bf(a.y); r[2] = f2bf(a.z); r[3] = f2bf(a.w);
    r[4] = f2bf(b.x); r[5] = f2bf(b.y); r[6] = f2bf(b.z); r[7] = f2bf(b.w);
    return r;
}

static __device__ __forceinline__ short8 ldbf(const unsigned short* __restrict__ p) {
    return *(const short8*)p;  // 16 B
}

// Pack weights to bf16 in ws: [dir][gate][j][k], k<512 -> Wih, k>=512 -> Whh. 6.29 MB.
// Also resets the 8 per-chain sync counters (stride 1, round-2 form).
__global__ __launch_bounds__(256) void convert_w_kernel(
    const float* __restrict__ Wih_f, const float* __restrict__ Whh_f,
    const float* __restrict__ Wih_b, const float* __restrict__ Whh_b,
    unsigned short* __restrict__ wsW, unsigned int* __restrict__ flags)
{
    if (flags && blockIdx.x == 0 && threadIdx.x < 8) flags[threadIdx.x] = 0u;
    const int total4 = 2 * 3 * HH * 1024 / 4;
    for (int i = blockIdx.x * 256 + threadIdx.x; i < total4; i += gridDim.x * 256) {
        const int e   = i * 4;
        const int k   = e & 1023;
        const int row = e >> 10;          // 0..3071
        const int dir = row / 1536;
        const int rem = row - dir * 1536;
        const int g   = rem >> 9;         // 0..2
        const int j   = rem & 511;
        const float* W = (k < 512) ? (dir ? Wih_b : Wih_f) : (dir ? Whh_b : Whh_f);
        const int kk = k & 511;
        const float4 v = *(const float4*)&W[(size_t)(g * HH + j) * II + kk];
        unsigned short o[4] = { (unsigned short)f2bf(v.x), (unsigned short)f2bf(v.y),
                                (unsigned short)f2bf(v.z), (unsigned short)f2bf(v.w) };
        *(ushort4*)&wsW[e] = *(ushort4*)o;
    }
}

// gi[dir][t][g][j][b] = (x[t] @ Wih^T)[b][g*H+j] + bih[g*H+j]   (fp32)
__global__ __launch_bounds__(256, 4) void gi_kernel(
    const float* __restrict__ inp,
    const float* __restrict__ bih_f, const float* __restrict__ bih_b,
    const unsigned short* __restrict__ wsW,
    float* __restrict__ gi)
{
    const int t    = blockIdx.x;
    const int dir  = blockIdx.y;
    const int w    = threadIdx.x >> 6;
    const int lane = threadIdx.x & 63;
    const int nm = lane & 15, kq = lane >> 4;

    short8 af[16];
    const float* xrow = inp + ((size_t)t * BB + w * 16 + nm) * II + kq * 8;
    #pragma unroll
    for (int kf = 0; kf < 16; ++kf) af[kf] = ldcvt(xrow + kf * 32);

    const float* bih = dir ? bih_b : bih_f;

    for (int g = 0; g < 3; ++g) {
        for (int jt = 0; jt < 32; ++jt) {
            f32x4 acc = {0.f, 0.f, 0.f, 0.f};
            const unsigned short* wb =
                wsW + ((size_t)((dir * 3 + g) * HH) + jt * 16 + nm) * 1024 + kq * 8;
            #pragma unroll
            for (int kf = 0; kf < 16; ++kf)
                acc = __builtin_amdgcn_mfma_f32_16x16x32_bf16(af[kf], ldbf(wb + kf * 32),
                                                              acc, 0, 0, 0);
            const int jj = jt * 16 + nm;
            const float bias = bih[g * HH + jj];
            float4 o;
            o.x = acc[0] + bias; o.y = acc[1] + bias;
            o.z = acc[2] + bias; o.w = acc[3] + bias;
            *(float4*)(gi + (((size_t)dir * TT + t) * 3 + g) * (HH * BB)
                         + (size_t)jj * BB + w * 16 + kq * 4) = o;
        }
    }
}

// Persistent cooperative chain kernel. 32 WGs x 512 threads (8 waves) -- round-2 topology.
// chain = bid & 7, quarter = bid >> 3; chain -> mt = chain & 3, dir = chain >> 2.
// Wave wid owns j = quarter*128 + wid*16 + nm for all 3 gates (192 weight regs).
// h tile staged global->LDS each step; A-fragments read per-kf from LDS (4 live regs).
__global__ __launch_bounds__(512, 2) void gru_chain_coop(
    const float* __restrict__ h0f, const float* __restrict__ h0b,
    const float* __restrict__ bhh_f, const float* __restrict__ bhh_b,
    const unsigned short* __restrict__ wsW,
    const float* __restrict__ gi,
    unsigned short* __restrict__ hbuf,   // [2][8][16][512] bf16
    unsigned int* __restrict__ flags,    // [8] epoch counters
    float* __restrict__ out)
{
    __shared__ __align__(16) unsigned char hlds[16 * 1024];  // 16 rows x 512 bf16, swizzled

    const int bid     = blockIdx.x;
    const int chain   = bid & 7;
    const int quarter = bid >> 3;
    const int mt  = chain & 3;
    const int dir = chain >> 2;
    const int tid  = threadIdx.x;        // 0..511
    const int wid  = tid >> 6;           // 0..7
    const int lane = tid & 63;
    const int nm = lane & 15, kq = lane >> 4;
    const int j = quarter * 128 + wid * 16 + nm;   // this lane's gate column

    // ---- register-resident Whh fragments (48 frags = 192 regs) ----
    short8 wfr[16], wfz[16], wfn[16];
    {
        const unsigned short* w0 =
            wsW + ((size_t)((dir * 3 + 0) * HH) + j) * 1024 + 512 + kq * 8;
        const unsigned short* w1 = w0 + (size_t)HH * 1024;
        const unsigned short* w2 = w0 + (size_t)2 * HH * 1024;
        #pragma unroll
        for (int kf = 0; kf < 16; ++kf) {
            wfr[kf] = ldbf(w0 + kf * 32);
            wfz[kf] = ldbf(w1 + kf * 32);
            wfn[kf] = ldbf(w2 + kf * 32);
        }
    }

    const float* bhh = dir ? bhh_b : bhh_f;
    const float bhr = bhh[j], bhz = bhh[HH + j], bhn = bhh[2 * HH + j];

    // ---- stage h0 -> hbuf[0][chain] (each WG writes the full, identical copy) ----
    const float* h0 = dir ? h0b : h0f;
    {
        unsigned short* hb0 = hbuf + (size_t)chain * (16 * 512);
        const int bl = tid >> 5;          // 0..15
        const int k0 = (tid & 31) * 16;   // 0..496
        const float* p = h0 + (size_t)(mt * 16 + bl) * HH + k0;
        *(short8*)(hb0 + (size_t)bl * 512 + k0)     = ldcvt(p);
        *(short8*)(hb0 + (size_t)bl * 512 + k0 + 8) = ldcvt(p + 8);
    }
    float hprev[4];
    #pragma unroll
    for (int rg = 0; rg < 4; ++rg)
        hprev[rg] = h0[(size_t)(mt * 16 + kq * 4 + rg) * HH + j];
    __syncthreads();

    unsigned int* ctr = flags + chain;

    // gi for step 0, prefetched
    f32x4 gr, gz, gn;
    {
        const int t0 = dir ? (TT - 1) : 0;
        const float* gb = gi + (((size_t)dir * TT + t0) * 3) * (HH * BB)
                             + (size_t)j * BB + mt * 16 + kq * 4;
        gr = *(const f32x4*)(gb);
        gz = *(const f32x4*)(gb + HH * BB);
        gn = *(const f32x4*)(gb + 2 * HH * BB);
    }

    float* hT = out + (size_t)TT * BB * 2 * HH + (size_t)dir * BB * HH;

    for (int s = 0; s < TT; ++s) {
        const int t = dir ? (TT - 1 - s) : s;
        const unsigned short* hb = hbuf + ((size_t)(s & 1) * 8 + chain) * (16 * 512);
        unsigned short* hw = hbuf + ((size_t)((s + 1) & 1) * 8 + chain) * (16 * 512);

        // ---- stage h (global -> LDS, XOR-swizzled rows) ----
        {
            const int r  = tid >> 5;          // 0..15
            const int c0 = (tid & 31) * 16;   // 0..496
            const short8 v0 = ldbf(hb + (size_t)r * 512 + c0);
            const short8 v1 = ldbf(hb + (size_t)r * 512 + c0 + 8);
            const int swz = (r & 7) << 4;
            char* base = (char*)hlds + r * 1024;
            *(short8*)(base + ((c0 * 2) ^ swz))        = v0;
            *(short8*)(base + (((c0 + 8) * 2) ^ swz))  = v1;
        }
        __syncthreads();

        // ---- MFMA: A-frag per kf from LDS, B = register-resident Whh ----
        f32x4 ar = {0.f, 0.f, 0.f, 0.f};
        f32x4 az = ar, an = ar;
        {
            const char* arow = (const char*)hlds + nm * 1024;
            const int aswz = (nm & 7) << 4;
            #pragma unroll
            for (int kf = 0; kf < 16; ++kf) {
                const short8 a = *(const short8*)(arow + ((kq * 16 + kf * 64) ^ aswz));
                ar = __builtin_amdgcn_mfma_f32_16x16x32_bf16(a, wfr[kf], ar, 0, 0, 0);
                az = __builtin_amdgcn_mfma_f32_16x16x32_bf16(a, wfz[kf], az, 0, 0, 0);
                an = __builtin_amdgcn_mfma_f32_16x16x32_bf16(a, wfn[kf], an, 0, 0, 0);
            }
        }

        // ---- epilogue: gates + blend; out fp32, next h state bf16 (global) ----
        float* orow = out + ((size_t)t * BB + mt * 16 + kq * 4) * (2 * HH) + dir * HH + j;
        #pragma unroll
        for (int rg = 0; rg < 4; ++rg) {
            const float r = 1.f / (1.f + __expf(-(ar[rg] + gr[rg] + bhr)));
            const float z = 1.f / (1.f + __expf(-(az[rg] + gz[rg] + bhz)));
            const float n = tanhf(gn[rg] + r * (an[rg] + bhn));
            const float h = (1.f - z) * n + z * hprev[rg];
            hprev[rg] = h;
            orow[(size_t)rg * 2 * HH] = h;
            hw[(size_t)(kq * 4 + rg) * 512 + j] = (unsigned short)f2bf(h);
        }

        if (s == TT - 1) {
            #pragma unroll
            for (int rg = 0; rg < 4; ++rg)
                hT[(size_t)(mt * 16 + kq * 4 + rg) * HH + j] = hprev[rg];
        } else {
            // prefetch next step's gi across the barrier (read-only data)
            const int tn = dir ? (TT - 2 - s) : (s + 1);
            const float* gb = gi + (((size_t)dir * TT + tn) * 3) * (HH * BB)
                                 + (size_t)j * BB + mt * 16 + kq * 4;
            gr = *(const f32x4*)(gb);
            gz = *(const f32x4*)(gb + HH * BB);
            gn = *(const f32x4*)(gb + 2 * HH * BB);

            // per-chain epoch barrier (4 WGs) -- round-2 protocol, verbatim
            __syncthreads();
            if (tid == 0) {
                __hip_atomic_fetch_add(ctr, 1u, __ATOMIC_RELEASE, __HIP_MEMORY_SCOPE_AGENT);
                const unsigned int want = 4u * (unsigned int)(s + 1);
                while (__hip_atomic_load(ctr, __ATOMIC_ACQUIRE,
                                         __HIP_MEMORY_SCOPE_AGENT) < want)
                    __builtin_amdgcn_s_sleep(1);
            }
            __syncthreads();
        }
    }
}

// ---------------- fallback: per-step kernel (round-0 verified) ----------------
template <bool USE_WS>
__global__ __launch_bounds__(64) void gru_step_kernel(
    const float* __restrict__ inp,
    const float* __restrict__ h0f, const float* __restrict__ h0b,
    const float* __restrict__ Wih_f, const float* __restrict__ Whh_f,
    const float* __restrict__ bih_f, const float* __restrict__ bhh_f,
    const float* __restrict__ Wih_b, const float* __restrict__ Whh_b,
    const float* __restrict__ bih_b, const float* __restrict__ bhh_b,
    const unsigned short* __restrict__ wsW,
    float* __restrict__ out, int s)
{
    const int jt   = blockIdx.x;
    const int mt   = blockIdx.y;
    const int dir  = blockIdx.z;
    const int lane = threadIdx.x;
    const int nm   = lane & 15;
    const int kq   = lane >> 4;
    const int j0   = jt * 16;
    const int koff = kq * 8;

    const int t  = dir ? (TT - 1 - s) : s;
    const int tp = dir ? (t + 1) : (t - 1);

    const float* Wih = dir ? Wih_b : Wih_f;
    const float* Whh = dir ? Whh_b : Whh_f;
    const float* bih = dir ? bih_b : bih_f;
    const float* bhh = dir ? bhh_b : bhh_f;
    const float* h0  = dir ? h0b : h0f;

    const int arow = mt * 16 + nm;

    const float* xrow = inp + ((size_t)t * BB + arow) * II;
    const float* hrow = (s == 0) ? (h0 + (size_t)arow * HH)
                                 : (out + ((size_t)tp * BB + arow) * 2 * HH + dir * HH);

    const unsigned short* wb0 = nullptr; const unsigned short* wb1 = nullptr;
    const unsigned short* wb2 = nullptr;
    if (USE_WS) {
        const size_t base = ((size_t)(dir * 3 + 0) * HH + (j0 + nm)) * 1024;
        wb0 = wsW + base;
        wb1 = wsW + base + (size_t)HH * 1024;
        wb2 = wsW + base + (size_t)2 * HH * 1024;
    }
    const float* wi0 = Wih + (size_t)(0 * HH + j0 + nm) * II;
    const float* wi1 = Wih + (size_t)(1 * HH + j0 + nm) * II;
    const float* wi2 = Wih + (size_t)(2 * HH + j0 + nm) * II;
    const float* wh0 = Whh + (size_t)(0 * HH + j0 + nm) * II;
    const float* wh1 = Whh + (size_t)(1 * HH + j0 + nm) * II;
    const float* wh2 = Whh + (size_t)(2 * HH + j0 + nm) * II;

    f32x4 ar = {0.f, 0.f, 0.f, 0.f};
    f32x4 az = ar, ain = ar, ahn = ar;

    #pragma unroll 4
    for (int k0 = 0; k0 < II; k0 += 32) {
        const int kk = k0 + koff;
        const short8 a  = ldcvt(xrow + kk);
        const short8 b0 = USE_WS ? ldbf(wb0 + kk) : ldcvt(wi0 + kk);
        const short8 b1 = USE_WS ? ldbf(wb1 + kk) : ldcvt(wi1 + kk);
        const short8 b2 = USE_WS ? ldbf(wb2 + kk) : ldcvt(wi2 + kk);
        ar  = __builtin_amdgcn_mfma_f32_16x16x32_bf16(a, b0, ar, 0, 0, 0);
        az  = __builtin_amdgcn_mfma_f32_16x16x32_bf16(a, b1, az, 0, 0, 0);
        ain = __builtin_amdgcn_mfma_f32_16x16x32_bf16(a, b2, ain, 0, 0, 0);
    }
    #pragma unroll 4
    for (int k0 = 0; k0 < HH; k0 += 32) {
        const int kk = k0 + koff;
        const short8 a  = ldcvt(hrow + kk);
        const short8 b0 = USE_WS ? ldbf(wb0 + 512 + kk) : ldcvt(wh0 + kk);
        const short8 b1 = USE_WS ? ldbf(wb1 + 512 + kk) : ldcvt(wh1 + kk);
        const short8 b2 = USE_WS ? ldbf(wb2 + 512 + kk) : ldcvt(wh2 + kk);
        ar  = __builtin_amdgcn_mfma_f32_16x16x32_bf16(a, b0, ar, 0, 0, 0);
        az  = __builtin_amdgcn_mfma_f32_16x16x32_bf16(a, b1, az, 0, 0, 0);
        ahn = __builtin_amdgcn_mfma_f32_16x16x32_bf16(a, b2, ahn, 0, 0, 0);
    }

    const int jg = j0 + nm;
    const float b_ir = bih[jg], b_iz = bih[HH + jg], b_in = bih[2 * HH + jg];
    const float b_hr = bhh[jg], b_hz = bhh[HH + jg], b_hn = bhh[2 * HH + jg];

    #pragma unroll
    for (int rg = 0; rg < 4; ++rg) {
        const int be = mt * 16 + kq * 4 + rg;
        const float hprevv = (s == 0)
            ? h0[(size_t)be * HH + jg]
            : out[((size_t)tp * BB + be) * 2 * HH + dir * HH + jg];
        const float r = 1.f / (1.f + __expf(-(ar[rg] + b_ir + b_hr)));
        const float z = 1.f / (1.f + __expf(-(az[rg] + b_iz + b_hz)));
        const float n = tanhf(ain[rg] + b_in + r * (ahn[rg] + b_hn));
        const float hnew = (1.f - z) * n + z * hprevv;
        out[((size_t)t * BB + be) * 2 * HH + dir * HH + jg] = hnew;
        if (s == TT - 1) {
            float* hTp = out + (size_t)TT * BB * 2 * HH + (size_t)dir * BB * HH;
            hTp[(size_t)be * HH + jg] = hnew;
        }
    }
}

extern "C" void kernel_launch(void* const* d_in, const int* in_sizes, int n_in,
                              void* d_out, int out_size, void* d_ws, size_t ws_size,
                              hipStream_t stream) {
    (void)in_sizes; (void)n_in; (void)out_size;

    const float* inp   = (const float*)d_in[0];
    const float* h0f   = (const float*)d_in[1];
    const float* h0b   = (const float*)d_in[2];
    const float* Wih_f = (const float*)d_in[3];
    const float* Whh_f = (const float*)d_in[4];
    const float* bih_f = (const float*)d_in[5];
    const float* bhh_f = (const float*)d_in[6];
    const float* Wih_b = (const float*)d_in[7];
    const float* Whh_b = (const float*)d_in[8];
    const float* bih_b = (const float*)d_in[9];
    const float* bhh_b = (const float*)d_in[10];
    float* out = (float*)d_out;

    const size_t W_BYTES  = (size_t)2 * 3 * HH * 1024 * sizeof(unsigned short);   // 6.29 MB
    const size_t GI_BYTES = (size_t)2 * TT * 3 * HH * BB * sizeof(float);         // 402.7 MB
    const size_t HB_BYTES = (size_t)2 * 8 * 16 * 512 * sizeof(unsigned short);    // 256 KB
    const size_t FL_BYTES = 256;

    if (ws_size >= W_BYTES + GI_BYTES + HB_BYTES + FL_BYTES) {
        unsigned short* wsW  = (unsigned short*)d_ws;
        float*          gi   = (float*)((char*)d_ws + W_BYTES);
        unsigned short* hbuf = (unsigned short*)((char*)d_ws + W_BYTES + GI_BYTES);
        unsigned int*   flags = (unsigned int*)((char*)d_ws + W_BYTES + GI_BYTES + HB_BYTES);

        convert_w_kernel<<<1024, 256, 0, stream>>>(Wih_f, Whh_f, Wih_b, Whh_b, wsW, flags);
        gi_kernel<<<dim3(TT, 2), 256, 0, stream>>>(inp, bih_f, bih_b, wsW, gi);

        void* args[] = { (void*)&h0f, (void*)&h0b, (void*)&bhh_f, (void*)&bhh_b,
                         (void*)&wsW, (void*)&gi, (void*)&hbuf, (void*)&flags,
                         (void*)&out };
        hipLaunchCooperativeKernel((const void*)gru_chain_coop,
                                   dim3(32), dim3(512), args, 0, stream);
    } else if (ws_size >= W_BYTES) {
        unsigned short* wsW = (unsigned short*)d_ws;
        convert_w_kernel<<<1024, 256, 0, stream>>>(Wih_f, Whh_f, Wih_b, Whh_b, wsW, nullptr);
        const dim3 grid(HH / 16, BB / 16, 2);
        for (int s = 0; s < TT; ++s) {
            gru_step_kernel<true><<<grid, dim3(64), 0, stream>>>(
                inp, h0f, h0b, Wih_f, Whh_f, bih_f, bhh_f,
                Wih_b, Whh_b, bih_b, bhh_b, wsW, out, s);
        }
    } else {
        const dim3 grid(HH / 16, BB / 16, 2);
        for (int s = 0; s < TT; ++s) {
            gru_step_kernel<false><<<grid, dim3(64), 0, stream>>>(
                inp, h0f, h0b, Wih_f, Whh_f, bih_f, bhh_f,
                Wih_b, Whh_b, bih_b, bhh_b, nullptr, out, s);
        }
    }
}